// Round 2
// baseline (240.963 us; speedup 1.0000x reference)
//
#include <hip/hip_runtime.h>
#include <stdint.h>

typedef unsigned short u16;
typedef __attribute__((ext_vector_type(8))) short bf16x8;
typedef __attribute__((ext_vector_type(4))) float f32x4;

// ---- constants (problem shape) ----
#define Bsz   8192
#define Vv    4000
#define Ee    256
#define Uu    256
#define INd   512
#define G3    768   // 3*U

__device__ __forceinline__ u16 f2bf(float f) {
    union { float f; uint32_t i; } v; v.f = f;
    uint32_t x = v.i;
    return (u16)((x + 0x7fffu + ((x >> 16) & 1u)) >> 16);  // RNE
}

// ---- x = bf16(concat(features[b], emb[tokens[b]])) : [B x 512] ----
__global__ __launch_bounds__(256) void gather_x(
    const int* __restrict__ tokens, const float* __restrict__ features,
    const float* __restrict__ emb, u16* __restrict__ x)
{
    int id = blockIdx.x * 256 + threadIdx.x;   // B*64 chunks of 8
    int b = id >> 6;
    int k = (id & 63) * 8;
    const float* src = (k < Ee) ? (features + (size_t)b * Ee + k)
                                : (emb + (size_t)tokens[b] * Ee + (k - Ee));
    float4 a = *(const float4*)src;
    float4 c = *(const float4*)(src + 4);
    u16 o[8] = {f2bf(a.x), f2bf(a.y), f2bf(a.z), f2bf(a.w),
                f2bf(c.x), f2bf(c.y), f2bf(c.z), f2bf(c.w)};
    *(uint4*)(x + (size_t)b * INd + k) = *(uint4*)o;
}

// ---- out[N][K](bf16) = bf16(in[K][N]^T), K = 1<<logK ----
__global__ __launch_bounds__(256) void transpose_cvt(
    const float* __restrict__ in, u16* __restrict__ out, int logK, int N)
{
    int id = blockIdx.x * 256 + threadIdx.x;
    int n = id >> logK;
    int k = id & ((1 << logK) - 1);
    out[id] = f2bf(in[(size_t)k * N + n]);
}

#define BM 64
#define BN 64
#define BK 32
#define LDP 56   // padded lds row stride (u16): 112B, max 2-way bank alias (free)

// ---- fused GEMM1 + GRU cell:  h = (1-z)*n  (h0 = 0) ----
// block tile: 64 batch rows x 64 h-cols; 3 gate GEMMs (z,r,n) share the A tile.
__global__ __launch_bounds__(256) void gemm_gru(
    const u16* __restrict__ A,     // x [B x 512] bf16
    const u16* __restrict__ BT,    // w1t [768 x 512] bf16
    const float* __restrict__ gb,  // gru_bias [2 x 768] f32
    u16* __restrict__ h,           // [B x 256] bf16 (ws)
    float* __restrict__ state)     // [B x 256] f32 (output 1)
{
    __shared__ u16 As[BM][LDP];
    __shared__ u16 Bs[3][BN][LDP];

    int tid  = threadIdx.x;
    int m0   = blockIdx.y * BM;
    int n0   = blockIdx.x * BN;    // h-col tile, n0 in [0,256)
    int wid  = tid >> 6;
    int lane = tid & 63;
    int quad = lane >> 4;
    int l16  = lane & 15;
    int wm   = (wid >> 1) * 32;
    int wn   = (wid & 1) * 32;

    f32x4 acc[3][2][2] = {};

    int ldr = tid >> 2;
    int ldc = (tid & 3) * 8;

    const u16* Arow = A + (size_t)(m0 + ldr) * INd + ldc;
    const u16* B0 = BT + (size_t)(n0 + ldr) * INd + ldc;          // z cols
    const u16* B1 = BT + (size_t)(Uu + n0 + ldr) * INd + ldc;     // r cols
    const u16* B2 = BT + (size_t)(2 * Uu + n0 + ldr) * INd + ldc; // n cols

    for (int k0 = 0; k0 < INd; k0 += BK) {
        __syncthreads();
        *(uint4*)&As[ldr][ldc]    = *(const uint4*)(Arow + k0);
        *(uint4*)&Bs[0][ldr][ldc] = *(const uint4*)(B0 + k0);
        *(uint4*)&Bs[1][ldr][ldc] = *(const uint4*)(B1 + k0);
        *(uint4*)&Bs[2][ldr][ldc] = *(const uint4*)(B2 + k0);
        __syncthreads();

        bf16x8 af0 = *(const bf16x8*)&As[wm + l16][quad * 8];
        bf16x8 af1 = *(const bf16x8*)&As[wm + 16 + l16][quad * 8];
        #pragma unroll
        for (int g = 0; g < 3; g++) {
            bf16x8 bf0 = *(const bf16x8*)&Bs[g][wn + l16][quad * 8];
            bf16x8 bf1 = *(const bf16x8*)&Bs[g][wn + 16 + l16][quad * 8];
            acc[g][0][0] = __builtin_amdgcn_mfma_f32_16x16x32_bf16(af0, bf0, acc[g][0][0], 0, 0, 0);
            acc[g][0][1] = __builtin_amdgcn_mfma_f32_16x16x32_bf16(af0, bf1, acc[g][0][1], 0, 0, 0);
            acc[g][1][0] = __builtin_amdgcn_mfma_f32_16x16x32_bf16(af1, bf0, acc[g][1][0], 0, 0, 0);
            acc[g][1][1] = __builtin_amdgcn_mfma_f32_16x16x32_bf16(af1, bf1, acc[g][1][1], 0, 0, 0);
        }
    }

    // epilogue: C/D layout col=l16, row=quad*4+r (verified)
    #pragma unroll
    for (int mi = 0; mi < 2; mi++)
    #pragma unroll
    for (int ni = 0; ni < 2; ni++) {
        int j = n0 + wn + ni * 16 + l16;       // h-col in [0,256)
        float bz = gb[j]          + gb[G3 + j];
        float br = gb[Uu + j]     + gb[G3 + Uu + j];
        float b0n = gb[2 * Uu + j];
        float b1n = gb[G3 + 2 * Uu + j];
        #pragma unroll
        for (int r = 0; r < 4; r++) {
            int b = m0 + wm + mi * 16 + quad * 4 + r;
            float z  = 1.f / (1.f + __expf(-(acc[0][mi][ni][r] + bz)));
            float rr = 1.f / (1.f + __expf(-(acc[1][mi][ni][r] + br)));
            float n  = tanhf(acc[2][mi][ni][r] + b0n + rr * b1n);
            float hv = (1.f - z) * n;
            h[(size_t)b * Uu + j] = f2bf(hv);
            state[(size_t)b * Uu + j] = hv;
        }
    }
}

// ---- generic MFMA GEMM: C[MxN] = A[MxK](bf16) @ BT[NxK]^T(bf16) + bias[N](f32) ----
template<bool OUT_BF16>
__global__ __launch_bounds__(256) void gemm_bias(
    const u16* __restrict__ A, const u16* __restrict__ BT,
    const float* __restrict__ bias, void* __restrict__ Cout,
    int M, int N, int K)
{
    __shared__ u16 As[BM][LDP];
    __shared__ u16 Bs[BN][LDP];

    int tid  = threadIdx.x;
    int m0   = blockIdx.y * BM;
    int n0   = blockIdx.x * BN;
    int wid  = tid >> 6;
    int lane = tid & 63;
    int quad = lane >> 4;
    int l16  = lane & 15;
    int wm   = (wid >> 1) * 32;
    int wn   = (wid & 1) * 32;

    f32x4 acc[2][2] = {};

    int ldr = tid >> 2;
    int ldc = (tid & 3) * 8;

    const u16* Arow = A + (size_t)(m0 + ldr) * K + ldc;
    int nB = n0 + ldr;
    const u16* Brow = BT + (size_t)nB * K + ldc;
    bool bvalid = nB < N;

    for (int k0 = 0; k0 < K; k0 += BK) {
        __syncthreads();
        *(uint4*)&As[ldr][ldc] = *(const uint4*)(Arow + k0);
        uint4 bv = bvalid ? *(const uint4*)(Brow + k0) : make_uint4(0u, 0u, 0u, 0u);
        *(uint4*)&Bs[ldr][ldc] = bv;
        __syncthreads();

        bf16x8 af0 = *(const bf16x8*)&As[wm + l16][quad * 8];
        bf16x8 af1 = *(const bf16x8*)&As[wm + 16 + l16][quad * 8];
        bf16x8 bf0 = *(const bf16x8*)&Bs[wn + l16][quad * 8];
        bf16x8 bf1 = *(const bf16x8*)&Bs[wn + 16 + l16][quad * 8];

        acc[0][0] = __builtin_amdgcn_mfma_f32_16x16x32_bf16(af0, bf0, acc[0][0], 0, 0, 0);
        acc[0][1] = __builtin_amdgcn_mfma_f32_16x16x32_bf16(af0, bf1, acc[0][1], 0, 0, 0);
        acc[1][0] = __builtin_amdgcn_mfma_f32_16x16x32_bf16(af1, bf0, acc[1][0], 0, 0, 0);
        acc[1][1] = __builtin_amdgcn_mfma_f32_16x16x32_bf16(af1, bf1, acc[1][1], 0, 0, 0);
    }

    #pragma unroll
    for (int mi = 0; mi < 2; mi++)
    #pragma unroll
    for (int ni = 0; ni < 2; ni++) {
        int gn = n0 + wn + ni * 16 + l16;
        if (gn >= N) continue;
        float bvv = bias[gn];
        #pragma unroll
        for (int r = 0; r < 4; r++) {
            int gm = m0 + wm + mi * 16 + quad * 4 + r;
            float v = acc[mi][ni][r] + bvv;
            if (OUT_BF16) ((u16*)Cout)[(size_t)gm * N + gn] = f2bf(v);
            else          ((float*)Cout)[(size_t)gm * N + gn] = v;
        }
    }
}

extern "C" void kernel_launch(void* const* d_in, const int* in_sizes, int n_in,
                              void* d_out, int out_size, void* d_ws, size_t ws_size,
                              hipStream_t stream)
{
    const int*   tokens   = (const int*)d_in[0];
    const float* features = (const float*)d_in[1];
    // d_in[2] = hidden (unused: reference GRU starts from zeros)
    const float* emb      = (const float*)d_in[3];
    const float* w1       = (const float*)d_in[4];   // [512 x 768]
    // d_in[5] = gru_rkernel (unused: h0 = 0)
    const float* gbias    = (const float*)d_in[6];   // [2 x 768]
    const float* fc1w     = (const float*)d_in[7];   // [256 x 256]
    const float* fc1b     = (const float*)d_in[8];
    const float* fc2w     = (const float*)d_in[9];   // [256 x 4000]
    const float* fc2b     = (const float*)d_in[10];

    float* logits = (float*)d_out;                       // [8192*4000] f32
    float* state  = logits + (size_t)Bsz * Vv;           // [8192*256] f32

    char* ws = (char*)d_ws;
    u16* x    = (u16*)(ws);                 //  8,388,608 B : [8192 x 512]
    u16* w1t  = (u16*)(ws +  8388608);      //    786,432 B : [768 x 512]
    u16* fc1t = (u16*)(ws +  9175040);      //    131,072 B : [256 x 256]
    u16* fc2t = (u16*)(ws +  9306112);      //  2,048,000 B : [4000 x 256]
    u16* h    = (u16*)(ws + 11354112);      //  4,194,304 B : [8192 x 256]
    u16* y    = (u16*)(ws + 15548416);      //  4,194,304 B : [8192 x 256]
    // total ws use: 19,742,720 B

    // stage 0: gather + weight transposes (f32 -> bf16)
    gather_x     <<<dim3(Bsz * 64 / 256), 256, 0, stream>>>(tokens, features, emb, x);
    transpose_cvt<<<dim3(G3 * INd / 256), 256, 0, stream>>>(w1,   w1t,  9, G3);
    transpose_cvt<<<dim3(Uu * Uu / 256),  256, 0, stream>>>(fc1w, fc1t, 8, Uu);
    transpose_cvt<<<dim3(Vv * Uu / 256),  256, 0, stream>>>(fc2w, fc2t, 8, Vv);

    // stage 1: fused gx-GEMM + GRU cell -> h (bf16, ws) and state (f32, out)
    gemm_gru<<<dim3(Uu / BN, Bsz / BM), 256, 0, stream>>>(x, w1t, gbias, h, state);

    // stage 2: y = h @ fc1 + b  (bf16, ws)
    gemm_bias<true><<<dim3(Uu / BN, Bsz / BM), 256, 0, stream>>>(
        h, fc1t, fc1b, (void*)y, Bsz, Uu, Uu);

    // stage 3: logits = y @ fc2 + b  (f32, out)
    gemm_bias<false><<<dim3((Vv + BN - 1) / BN, Bsz / BM), 256, 0, stream>>>(
        y, fc2t, fc2b, (void*)logits, Bsz, Vv, Uu);
}

// Round 3
// 232.092 us; speedup vs baseline: 1.0382x; 1.0382x over previous
//
#include <hip/hip_runtime.h>
#include <stdint.h>

typedef unsigned short u16;
typedef __attribute__((ext_vector_type(8))) short bf16x8;
typedef __attribute__((ext_vector_type(4))) float f32x4;

// ---- constants (problem shape) ----
#define Bsz   8192
#define Vv    4000
#define Vpad  4096
#define Ee    256
#define Uu    256
#define INd   512
#define G3    768   // 3*U

__device__ __forceinline__ u16 f2bf(float f) {
    union { float f; uint32_t i; } v; v.f = f;
    uint32_t x = v.i;
    return (u16)((x + 0x7fffu + ((x >> 16) & 1u)) >> 16);  // RNE
}

// async global->LDS, 16B per lane (dest must be wave-uniform base + lane*16)
__device__ __forceinline__ void gload16(const u16* g, u16* l) {
    __builtin_amdgcn_global_load_lds(
        (const __attribute__((address_space(1))) unsigned int*)g,
        (__attribute__((address_space(3))) unsigned int*)l, 16, 0, 0);
}

// ---- x = bf16(concat(features[b], emb[tokens[b]])) : [B x 512] ----
__global__ __launch_bounds__(256) void gather_x(
    const int* __restrict__ tokens, const float* __restrict__ features,
    const float* __restrict__ emb, u16* __restrict__ x)
{
    int id = blockIdx.x * 256 + threadIdx.x;   // B*64 chunks of 8
    int b = id >> 6;
    int k = (id & 63) * 8;
    const float* src = (k < Ee) ? (features + (size_t)b * Ee + k)
                                : (emb + (size_t)tokens[b] * Ee + (k - Ee));
    float4 a = *(const float4*)src;
    float4 c = *(const float4*)(src + 4);
    u16 o[8] = {f2bf(a.x), f2bf(a.y), f2bf(a.z), f2bf(a.w),
                f2bf(c.x), f2bf(c.y), f2bf(c.z), f2bf(c.w)};
    *(uint4*)(x + (size_t)b * INd + k) = *(uint4*)o;
}

// ---- all three weight transposes (f32 [K][N] -> bf16 [Nout][K]) in one kernel ----
// 32x32 LDS tiles, coalesced read+write. Zero-fills pad rows (n >= N).
// tiles: w1 768/32*512/32=384 | fc1 8*8=64 | fc2 4096/32*256/32=1024 -> 1472 blocks
__global__ __launch_bounds__(256) void transpose_all(
    const float* __restrict__ w1,  u16* __restrict__ w1t,
    const float* __restrict__ fc1, u16* __restrict__ fc1t,
    const float* __restrict__ fc2, u16* __restrict__ fc2t)
{
    __shared__ float t[32][33];
    int b = blockIdx.x;
    const float* in; u16* out; int K, N, bx, by;
    if (b < 384)      { in = w1;  out = w1t;  K = 512; N = 768;  bx = b % 24;  by = b / 24; }
    else if (b < 448) { b -= 384; in = fc1; out = fc1t; K = 256; N = 256;  bx = b % 8;   by = b / 8; }
    else              { b -= 448; in = fc2; out = fc2t; K = 256; N = Vv;   bx = b % 128; by = b / 128; }
    int n0 = bx * 32, k0 = by * 32;
    int c = threadIdx.x & 31, r = threadIdx.x >> 5;   // 8 rows per phase
    int n = n0 + c;
    #pragma unroll
    for (int i = 0; i < 32; i += 8)
        t[r + i][c] = (n < N) ? in[(size_t)(k0 + r + i) * N + n] : 0.f;
    __syncthreads();
    #pragma unroll
    for (int i = 0; i < 32; i += 8)
        out[(size_t)(n0 + r + i) * K + k0 + c] = f2bf(t[c][r + i]);
}

// ---- m97-style 128x128 GEMM: C[M x N] = A[M x K] @ BT[Nb x K]^T + bias ----
// 256 thr / 4 waves (2x2 of 64x64), BK=32, unpadded LDS, global_load_lds w=16
template<bool OUT_BF16>
__global__ __launch_bounds__(256) void gemm128(
    const u16* __restrict__ A, const u16* __restrict__ BT,
    const float* __restrict__ bias, void* __restrict__ Cout,
    int N, int K)   // N = real out cols; grid.x covers padded Nb/128
{
    __shared__ __align__(16) u16 As[128 * 32];
    __shared__ __align__(16) u16 Bs[128 * 32];

    int tid  = threadIdx.x;
    int m0   = blockIdx.y * 128;
    int n0   = blockIdx.x * 128;
    int wid  = tid >> 6;
    int lane = tid & 63;
    int quad = lane >> 4;
    int l16  = lane & 15;
    int wm   = (wid >> 1) * 64;
    int wn   = (wid & 1) * 64;

    f32x4 acc[4][4] = {};

    const u16* ag = A  + (size_t)(m0 + (tid >> 2)) * K + (tid & 3) * 8;
    const u16* bg = BT + (size_t)(n0 + (tid >> 2)) * K + (tid & 3) * 8;
    u16* lA = &As[tid * 8];
    u16* lB = &Bs[tid * 8];

    for (int k0 = 0; k0 < K; k0 += 32) {
        __syncthreads();
        gload16(ag + k0,            lA);
        gload16(ag + 64 * K + k0,   lA + 64 * 32);
        gload16(bg + k0,            lB);
        gload16(bg + 64 * K + k0,   lB + 64 * 32);
        __syncthreads();

        bf16x8 af[4], bf[4];
        #pragma unroll
        for (int i = 0; i < 4; i++)
            af[i] = *(const bf16x8*)&As[(wm + i * 16 + l16) * 32 + quad * 8];
        #pragma unroll
        for (int j = 0; j < 4; j++)
            bf[j] = *(const bf16x8*)&Bs[(wn + j * 16 + l16) * 32 + quad * 8];
        #pragma unroll
        for (int i = 0; i < 4; i++)
            #pragma unroll
            for (int j = 0; j < 4; j++)
                acc[i][j] = __builtin_amdgcn_mfma_f32_16x16x32_bf16(af[i], bf[j], acc[i][j], 0, 0, 0);
    }

    // C/D layout: col = l16, row = quad*4 + r (verified)
    #pragma unroll
    for (int i = 0; i < 4; i++)
    #pragma unroll
    for (int j = 0; j < 4; j++) {
        int gn = n0 + wn + j * 16 + l16;
        if (gn >= N) continue;
        float bvv = bias[gn];
        #pragma unroll
        for (int r = 0; r < 4; r++) {
            int gm = m0 + wm + i * 16 + quad * 4 + r;
            float v = acc[i][j][r] + bvv;
            if (OUT_BF16) ((u16*)Cout)[(size_t)gm * N + gn] = f2bf(v);
            else          ((float*)Cout)[(size_t)gm * N + gn] = v;
        }
    }
}

// ---- fused GEMM1 + GRU cell (h0=0): tile 128 batch x 64 h-cols x 3 gates ----
__global__ __launch_bounds__(256) void gemm_gru(
    const u16* __restrict__ A,     // x [B x 512] bf16
    const u16* __restrict__ BT,    // w1t [768 x 512] bf16
    const float* __restrict__ gb,  // gru_bias [2 x 768] f32
    u16* __restrict__ h,           // [B x 256] bf16
    float* __restrict__ state)     // [B x 256] f32 (output 1)
{
    __shared__ __align__(16) u16 As[128 * 32];
    __shared__ __align__(16) u16 Bs[3][64 * 32];

    int tid  = threadIdx.x;
    int m0   = blockIdx.y * 128;
    int n0   = blockIdx.x * 64;    // h-col tile, n0 in {0,64,128,192}
    int wid  = tid >> 6;
    int lane = tid & 63;
    int quad = lane >> 4;
    int l16  = lane & 15;
    int wm   = wid * 32;           // wave owns 32 rows x all 64 cols

    f32x4 acc[3][2][4] = {};

    const u16* ag = A  + (size_t)(m0 + (tid >> 2)) * INd + (tid & 3) * 8;
    const u16* bg = BT + (size_t)(n0 + (tid >> 2)) * INd + (tid & 3) * 8;
    u16* lA = &As[tid * 8];
    u16* lB = &Bs[0][tid * 8];

    for (int k0 = 0; k0 < INd; k0 += 32) {
        __syncthreads();
        gload16(ag + k0,           lA);
        gload16(ag + 64 * INd + k0, lA + 64 * 32);
        #pragma unroll
        for (int g = 0; g < 3; g++)
            gload16(bg + (size_t)g * 256 * INd + k0, lB + g * 64 * 32);
        __syncthreads();

        bf16x8 af[2];
        #pragma unroll
        for (int i = 0; i < 2; i++)
            af[i] = *(const bf16x8*)&As[(wm + i * 16 + l16) * 32 + quad * 8];
        #pragma unroll
        for (int g = 0; g < 3; g++)
            #pragma unroll
            for (int j = 0; j < 4; j++) {
                bf16x8 bf = *(const bf16x8*)&Bs[g][(j * 16 + l16) * 32 + quad * 8];
                acc[g][0][j] = __builtin_amdgcn_mfma_f32_16x16x32_bf16(af[0], bf, acc[g][0][j], 0, 0, 0);
                acc[g][1][j] = __builtin_amdgcn_mfma_f32_16x16x32_bf16(af[1], bf, acc[g][1][j], 0, 0, 0);
            }
    }

    #pragma unroll
    for (int i = 0; i < 2; i++)
    #pragma unroll
    for (int j = 0; j < 4; j++) {
        int jj = n0 + j * 16 + l16;
        float bz  = gb[jj]          + gb[G3 + jj];
        float br  = gb[Uu + jj]     + gb[G3 + Uu + jj];
        float b0n = gb[2 * Uu + jj];
        float b1n = gb[G3 + 2 * Uu + jj];
        #pragma unroll
        for (int r = 0; r < 4; r++) {
            int b = m0 + wm + i * 16 + quad * 4 + r;
            float z  = 1.f / (1.f + __expf(-(acc[0][i][j][r] + bz)));
            float rr = 1.f / (1.f + __expf(-(acc[1][i][j][r] + br)));
            float n  = tanhf(acc[2][i][j][r] + b0n + rr * b1n);
            float hv = (1.f - z) * n;
            h[(size_t)b * Uu + jj] = f2bf(hv);
            state[(size_t)b * Uu + jj] = hv;
        }
    }
}

extern "C" void kernel_launch(void* const* d_in, const int* in_sizes, int n_in,
                              void* d_out, int out_size, void* d_ws, size_t ws_size,
                              hipStream_t stream)
{
    const int*   tokens   = (const int*)d_in[0];
    const float* features = (const float*)d_in[1];
    // d_in[2] = hidden (unused: reference GRU starts from zeros)
    const float* emb      = (const float*)d_in[3];
    const float* w1       = (const float*)d_in[4];   // [512 x 768]
    // d_in[5] = gru_rkernel (unused: h0 = 0)
    const float* gbias    = (const float*)d_in[6];   // [2 x 768]
    const float* fc1w     = (const float*)d_in[7];   // [256 x 256]
    const float* fc1b     = (const float*)d_in[8];
    const float* fc2w     = (const float*)d_in[9];   // [256 x 4000]
    const float* fc2b     = (const float*)d_in[10];

    float* logits = (float*)d_out;                       // [8192 x 4000] f32
    float* state  = logits + (size_t)Bsz * Vv;           // [8192 x 256] f32

    char* ws = (char*)d_ws;
    u16* x    = (u16*)(ws);                 //  8,388,608 B : [8192 x 512]
    u16* w1t  = (u16*)(ws +  8388608);      //    786,432 B : [768 x 512]
    u16* fc1t = (u16*)(ws +  9175040);      //    131,072 B : [256 x 256]
    u16* fc2t = (u16*)(ws +  9306112);      //  2,097,152 B : [4096 x 256] (pad zeroed)
    u16* h    = (u16*)(ws + 11403264);      //  4,194,304 B : [8192 x 256]
    u16* y    = (u16*)(ws + 15597568);      //  4,194,304 B : [8192 x 256]
    // total ws use: 19,791,872 B

    gather_x<<<dim3(Bsz * 64 / 256), 256, 0, stream>>>(tokens, features, emb, x);
    transpose_all<<<dim3(1472), 256, 0, stream>>>(w1, w1t, fc1w, fc1t, fc2w, fc2t);

    // fused gx-GEMM + GRU -> h (bf16) and state (f32 out)
    gemm_gru<<<dim3(Uu / 64, Bsz / 128), 256, 0, stream>>>(x, w1t, gbias, h, state);

    // y = h @ fc1 + b (bf16)
    gemm128<true><<<dim3(Uu / 128, Bsz / 128), 256, 0, stream>>>(
        h, fc1t, fc1b, (void*)y, Uu, Uu);

    // logits = y @ fc2 + b (f32 out), padded col grid, guarded epilogue
    gemm128<false><<<dim3(Vpad / 128, Bsz / 128), 256, 0, stream>>>(
        y, fc2t, fc2b, (void*)logits, Vv, Uu);
}

// Round 4
// 221.280 us; speedup vs baseline: 1.0889x; 1.0489x over previous
//
#include <hip/hip_runtime.h>
#include <stdint.h>

typedef unsigned short u16;
typedef __attribute__((ext_vector_type(8))) short bf16x8;
typedef __attribute__((ext_vector_type(4))) float f32x4;

// ---- constants (problem shape) ----
#define Bsz   8192
#define Vv    4000
#define Vpad  4096
#define Ee    256
#define Uu    256
#define INd   512
#define G3    768   // 3*U

__device__ __forceinline__ u16 f2bf(float f) {
    union { float f; uint32_t i; } v; v.f = f;
    uint32_t x = v.i;
    return (u16)((x + 0x7fffu + ((x >> 16) & 1u)) >> 16);  // RNE
}

// async global->LDS, 16B per lane (dest = wave-uniform base + lane*16)
__device__ __forceinline__ void gload16(const u16* g, u16* l) {
    __builtin_amdgcn_global_load_lds(
        (const __attribute__((address_space(1))) unsigned int*)g,
        (__attribute__((address_space(3))) unsigned int*)l, 16, 0, 0);
}

// ---- all three weight transposes (f32 [K][N] -> bf16 [Nout][K]) in one kernel ----
// 32x32 LDS tiles, coalesced read+write. Zero-fills pad rows (n >= N).
// tiles: w1 24*16=384 | fc1 8*8=64 | fc2 128*8=1024 -> 1472 blocks
__global__ __launch_bounds__(256) void transpose_all(
    const float* __restrict__ w1,  u16* __restrict__ w1t,
    const float* __restrict__ fc1, u16* __restrict__ fc1t,
    const float* __restrict__ fc2, u16* __restrict__ fc2t)
{
    __shared__ float t[32][33];
    int b = blockIdx.x;
    const float* in; u16* out; int K, N, bx, by;
    if (b < 384)      { in = w1;  out = w1t;  K = 512; N = 768;  bx = b % 24;  by = b / 24; }
    else if (b < 448) { b -= 384; in = fc1; out = fc1t; K = 256; N = 256;  bx = b % 8;   by = b / 8; }
    else              { b -= 448; in = fc2; out = fc2t; K = 256; N = Vv;   bx = b % 128; by = b / 128; }
    int n0 = bx * 32, k0 = by * 32;
    int c = threadIdx.x & 31, r = threadIdx.x >> 5;   // 8 rows per phase
    int n = n0 + c;
    #pragma unroll
    for (int i = 0; i < 32; i += 8)
        t[r + i][c] = (n < N) ? in[(size_t)(k0 + r + i) * N + n] : 0.f;
    __syncthreads();
    #pragma unroll
    for (int i = 0; i < 32; i += 8)
        out[(size_t)(n0 + r + i) * K + k0 + c] = f2bf(t[c][r + i]);
}

// ---- fused gather + GEMM1 + GRU cell (h0=0): tile 64 batch x 64 h-cols x 3 gates ----
// A-operand gathered on the fly from f32 features/emb (no x buffer).
__global__ __launch_bounds__(256) void gru_fused(
    const int* __restrict__ tokens, const float* __restrict__ features,
    const float* __restrict__ emb,  const u16* __restrict__ BT,   // w1t [768 x 512] bf16
    const float* __restrict__ gb,   // gru_bias [2 x 768] f32
    u16* __restrict__ h,            // [B x 256] bf16 (ws)
    float* __restrict__ state)      // [B x 256] f32 (output 1)
{
    __shared__ __align__(16) u16 As[64 * 32];
    __shared__ __align__(16) u16 Bs[3][64 * 32];
    __shared__ int tok[64];

    int tid = threadIdx.x;
    int m0  = blockIdx.y * 64;
    int n0  = blockIdx.x * 64;     // h-col tile in {0,64,128,192}
    if (tid < 64) tok[tid] = tokens[m0 + tid];

    int wid = tid >> 6, lane = tid & 63, quad = lane >> 4, l16 = lane & 15;
    int wm = wid * 16;             // wave owns 16 rows x 64 cols x 3 gates

    f32x4 acc[3][4] = {};

    int r  = tid >> 2;             // 0..63 row
    int kc = (tid & 3) * 8;        // k-chunk within 32
    const u16* bg = BT + (size_t)(n0 + r) * INd + kc;
    u16* lB = &Bs[0][tid * 8];
    const float* fsrc = features + (size_t)(m0 + r) * Ee + kc;

    for (int k0 = 0; k0 < INd; k0 += 32) {
        __syncthreads();           // also publishes tok[] on first iter
        #pragma unroll
        for (int g = 0; g < 3; g++)
            gload16(bg + (size_t)g * 256 * INd + k0, lB + g * 64 * 32);
        const float* src = (k0 < Ee) ? (fsrc + k0)
                                     : (emb + (size_t)tok[r] * Ee + (k0 - Ee) + kc);
        float4 a = *(const float4*)src;
        float4 c = *(const float4*)(src + 4);
        u16 o[8] = {f2bf(a.x), f2bf(a.y), f2bf(a.z), f2bf(a.w),
                    f2bf(c.x), f2bf(c.y), f2bf(c.z), f2bf(c.w)};
        *(uint4*)&As[tid * 8] = *(uint4*)o;
        __syncthreads();

        bf16x8 af = *(const bf16x8*)&As[(wm + l16) * 32 + quad * 8];
        #pragma unroll
        for (int g = 0; g < 3; g++)
            #pragma unroll
            for (int j = 0; j < 4; j++) {
                bf16x8 bf = *(const bf16x8*)&Bs[g][(j * 16 + l16) * 32 + quad * 8];
                acc[g][j] = __builtin_amdgcn_mfma_f32_16x16x32_bf16(af, bf, acc[g][j], 0, 0, 0);
            }
    }

    // C/D layout: col = l16, row = quad*4 + r (verified)
    #pragma unroll
    for (int j = 0; j < 4; j++) {
        int jj = n0 + j * 16 + l16;
        float bz  = gb[jj]          + gb[G3 + jj];
        float br  = gb[Uu + jj]     + gb[G3 + Uu + jj];
        float b0n = gb[2 * Uu + jj];
        float b1n = gb[G3 + 2 * Uu + jj];
        #pragma unroll
        for (int rr = 0; rr < 4; rr++) {
            int b = m0 + wm + quad * 4 + rr;
            float z  = 1.f / (1.f + __expf(-(acc[0][j][rr] + bz)));
            float rg = 1.f / (1.f + __expf(-(acc[1][j][rr] + br)));
            float n  = tanhf(acc[2][j][rr] + b0n + rg * b1n);
            float hv = (1.f - z) * n;
            h[(size_t)b * Uu + jj] = f2bf(hv);
            state[(size_t)b * Uu + jj] = hv;
        }
    }
}

// ---- m97-style GEMM: C[M x N] = A[M x K](bf16) @ BT[Nb x K]^T(bf16) + bias ----
// 256 thr / 4 waves, BK=32, unpadded LDS, global_load_lds w=16
template<int BMt, int BNt, bool OUT_BF16>
__global__ __launch_bounds__(256) void gemm_bt(
    const u16* __restrict__ A, const u16* __restrict__ BT,
    const float* __restrict__ bias, void* __restrict__ Cout,
    int N, int K)   // N = real out cols (epilogue-guarded); grid covers padded cols
{
    constexpr int NW_N  = (BNt == 128) ? 2 : 1;   // waves along n
    constexpr int NW_M  = 4 / NW_N;               // waves along m
    constexpr int WROWS = BMt / NW_M;             // rows per wave
    constexpr int MI    = WROWS / 16;

    __shared__ __align__(16) u16 As[BMt * 32];
    __shared__ __align__(16) u16 Bs[BNt * 32];

    int tid  = threadIdx.x;
    int m0   = blockIdx.y * BMt;
    int n0   = blockIdx.x * BNt;
    int wid  = tid >> 6, lane = tid & 63, quad = lane >> 4, l16 = lane & 15;
    int wm   = (wid / NW_N) * WROWS;
    int wn   = (wid % NW_N) * 64;

    f32x4 acc[MI][4] = {};

    const u16* ag = A  + (size_t)(m0 + (tid >> 2)) * K + (tid & 3) * 8;
    const u16* bg = BT + (size_t)(n0 + (tid >> 2)) * K + (tid & 3) * 8;
    u16* lA = &As[tid * 8];
    u16* lB = &Bs[tid * 8];

    for (int k0 = 0; k0 < K; k0 += 32) {
        __syncthreads();
        #pragma unroll
        for (int s = 0; s < BMt / 64; s++)
            gload16(ag + (size_t)s * 64 * K + k0, lA + s * 64 * 32);
        #pragma unroll
        for (int s = 0; s < BNt / 64; s++)
            gload16(bg + (size_t)s * 64 * K + k0, lB + s * 64 * 32);
        __syncthreads();

        bf16x8 af[MI], bf[4];
        #pragma unroll
        for (int i = 0; i < MI; i++)
            af[i] = *(const bf16x8*)&As[(wm + i * 16 + l16) * 32 + quad * 8];
        #pragma unroll
        for (int j = 0; j < 4; j++)
            bf[j] = *(const bf16x8*)&Bs[(wn + j * 16 + l16) * 32 + quad * 8];
        #pragma unroll
        for (int i = 0; i < MI; i++)
            #pragma unroll
            for (int j = 0; j < 4; j++)
                acc[i][j] = __builtin_amdgcn_mfma_f32_16x16x32_bf16(af[i], bf[j], acc[i][j], 0, 0, 0);
    }

    // C/D layout: col = l16, row = quad*4 + r (verified)
    #pragma unroll
    for (int i = 0; i < MI; i++)
    #pragma unroll
    for (int j = 0; j < 4; j++) {
        int gn = n0 + wn + j * 16 + l16;
        if (gn >= N) continue;
        float bv = bias[gn];
        #pragma unroll
        for (int r = 0; r < 4; r++) {
            int gm = m0 + wm + i * 16 + quad * 4 + r;
            float v = acc[i][j][r] + bv;
            if (OUT_BF16) ((u16*)Cout)[(size_t)gm * N + gn] = f2bf(v);
            else          ((float*)Cout)[(size_t)gm * N + gn] = v;
        }
    }
}

extern "C" void kernel_launch(void* const* d_in, const int* in_sizes, int n_in,
                              void* d_out, int out_size, void* d_ws, size_t ws_size,
                              hipStream_t stream)
{
    const int*   tokens   = (const int*)d_in[0];
    const float* features = (const float*)d_in[1];
    // d_in[2] = hidden (unused: reference GRU starts from zeros)
    const float* emb      = (const float*)d_in[3];
    const float* w1       = (const float*)d_in[4];   // [512 x 768]
    // d_in[5] = gru_rkernel (unused: h0 = 0)
    const float* gbias    = (const float*)d_in[6];   // [2 x 768]
    const float* fc1w     = (const float*)d_in[7];   // [256 x 256]
    const float* fc1b     = (const float*)d_in[8];
    const float* fc2w     = (const float*)d_in[9];   // [256 x 4000]
    const float* fc2b     = (const float*)d_in[10];

    float* logits = (float*)d_out;                       // [8192 x 4000] f32
    float* state  = logits + (size_t)Bsz * Vv;           // [8192 x 256] f32

    char* ws = (char*)d_ws;
    u16* w1t  = (u16*)(ws);                 //    786,432 B : [768 x 512]
    u16* fc1t = (u16*)(ws +   786432);      //    131,072 B : [256 x 256]
    u16* fc2t = (u16*)(ws +   917504);      //  2,097,152 B : [4096 x 256] (pad zeroed)
    u16* h    = (u16*)(ws +  3014656);      //  4,194,304 B : [8192 x 256]
    u16* y    = (u16*)(ws +  7208960);      //  4,194,304 B : [8192 x 256]
    // total ws use: 11,403,264 B

    // prep: all weight transposes (f32 -> bf16, k-contiguous)
    transpose_all<<<dim3(1472), 256, 0, stream>>>(w1, w1t, fc1w, fc1t, fc2w, fc2t);

    // fused gather + gx-GEMM + GRU -> h (bf16) and state (f32 out)
    gru_fused<<<dim3(Uu / 64, Bsz / 64), 256, 0, stream>>>(
        tokens, features, emb, w1t, gbias, h, state);

    // y = h @ fc1 + b (bf16), 64x64 tiles for 512 blocks (2/CU)
    gemm_bt<64, 64, true><<<dim3(Uu / 64, Bsz / 64), 256, 0, stream>>>(
        h, fc1t, fc1b, (void*)y, Uu, Uu);

    // logits = y @ fc2 + b (f32 out), padded col grid, guarded epilogue
    gemm_bt<128, 128, false><<<dim3(Vpad / 128, Bsz / 128), 256, 0, stream>>>(
        y, fc2t, fc2b, (void*)logits, Vv, Uu);
}